// Round 1
// baseline (500.189 us; speedup 1.0000x reference)
//
#include <hip/hip_runtime.h>

typedef unsigned short u16;
typedef unsigned int u32;
typedef __attribute__((ext_vector_type(8))) short bf16x8;
typedef __attribute__((ext_vector_type(4))) float f32x4;

#define MFMA16 __builtin_amdgcn_mfma_f32_16x16x32_bf16

__device__ __forceinline__ u16 f2bf(float f) {
  u32 u = __builtin_bit_cast(u32, f);
  u = u + 0x7FFFu + ((u >> 16) & 1u);
  return (u16)(u >> 16);
}
__device__ __forceinline__ u32 pk2(float lo, float hi) {
  return (u32)f2bf(lo) | ((u32)f2bf(hi) << 16);
}

// ---------------- kernel 0: fp32 -> bf16 convert (x, Wq|Wk|Wv) ----------------
__global__ __launch_bounds__(256) void cvt_kernel(
    const float* __restrict__ x, const float* __restrict__ wq,
    const float* __restrict__ wk, const float* __restrict__ wv,
    u16* __restrict__ xbf, u16* __restrict__ wbf) {
  int idx = blockIdx.x * 256 + threadIdx.x;
  if (idx < 1048576) {  // 4*4096*256 / 4 float4's of x
    float4 v = ((const float4*)x)[idx];
    uint2 u; u.x = pk2(v.x, v.y); u.y = pk2(v.z, v.w);
    ((uint2*)xbf)[idx] = u;
  } else {
    int j = idx - 1048576;  // < 3*16384
    const float* W = (j < 16384) ? wq : (j < 32768) ? wk : wv;
    int k = j & 16383;
    float4 v = ((const float4*)W)[k];
    uint2 u; u.x = pk2(v.x, v.y); u.y = pk2(v.z, v.w);
    ((uint2*)wbf)[j] = u;
  }
}

// ---------------- kernel 1: QKV projection ----------------
// mat 0: Qs[s][e] = (x @ Wq^T) * (log2(e)/16)   (scale folded for base-2 online softmax)
// mat 1: Ks[s][e] =  x @ Wk^T
// mat 2: Vt[e][s] =  (x @ Wv^T)^T               (transposed so PV reads are contiguous)
__global__ __launch_bounds__(256, 2) void proj_kernel(
    const u16* __restrict__ xbf, const u16* __restrict__ wbf,
    u16* __restrict__ Qs, u16* __restrict__ Ks, u16* __restrict__ Vt) {
  int tile = blockIdx.x, mat = blockIdx.y;
  int tid = threadIdx.x, w = tid >> 6, lane = tid & 63, b15 = lane & 15, g = lane >> 4;
  int base = tile * 64 + w * 16;
  const u16* W = wbf + mat * 65536;
  const u16* Xp = xbf + (size_t)(base + b15) * 256;
  f32x4 acc[16] = {};
  if (mat < 2) {
#pragma unroll
    for (int kk = 0; kk < 8; ++kk) {
      bf16x8 xf = *(const bf16x8*)(Xp + kk * 32 + g * 8);
#pragma unroll
      for (int eb = 0; eb < 16; ++eb) {
        bf16x8 wf = *(const bf16x8*)(W + (size_t)(eb * 16 + b15) * 256 + kk * 32 + g * 8);
        acc[eb] = MFMA16(xf, wf, acc[eb], 0, 0, 0);  // D[s][e]
      }
    }
    float scale = (mat == 0) ? 0.0901684400555602f : 1.0f;  // log2(e)/16
    u16* dst = (mat == 0) ? Qs : Ks;
#pragma unroll
    for (int eb = 0; eb < 16; ++eb)
#pragma unroll
      for (int r = 0; r < 4; ++r)
        dst[(size_t)(base + g * 4 + r) * 256 + eb * 16 + b15] = f2bf(acc[eb][r] * scale);
  } else {
#pragma unroll
    for (int kk = 0; kk < 8; ++kk) {
      bf16x8 xf = *(const bf16x8*)(Xp + kk * 32 + g * 8);
#pragma unroll
      for (int eb = 0; eb < 16; ++eb) {
        bf16x8 wf = *(const bf16x8*)(W + (size_t)(eb * 16 + b15) * 256 + kk * 32 + g * 8);
        acc[eb] = MFMA16(wf, xf, acc[eb], 0, 0, 0);  // D[e][s]
      }
    }
    int sglob = base + b15;
    int b = sglob >> 12, sl = sglob & 4095;
#pragma unroll
    for (int eb = 0; eb < 16; ++eb)
#pragma unroll
      for (int r = 0; r < 4; ++r) {
        int e = eb * 16 + g * 4 + r;
        Vt[((size_t)(b * 256 + e) << 12) + sl] = f2bf(acc[eb][r]);
      }
  }
}

// ---------------- kernel 2: causal flash attention ----------------
// 256 blocks (1/CU). XCD-affinity swizzle: batch b lives on XCDs {2b,2b+1} so its
// K/V (4MB bf16) stays L2-resident. 4 waves share one 64-row q-tile; kv-tiles of
// 32 staged in LDS (pad: K row 528B, V row 80B -> conflict-free b128 reads),
// register-double-buffered (loads issued before compute, written after barrier).
__global__ __launch_bounds__(256, 1) void attn_kernel(
    const u16* __restrict__ Qs, const u16* __restrict__ Ks_,
    const u16* __restrict__ Vt_, float* __restrict__ out) {
  __shared__ u16 Klds[32 * 264];   // 32 rows x 528B
  __shared__ u16 Vlds[256 * 40];   // 256 rows x 80B

  int bx = blockIdx.x;
  int batch = (bx & 7) >> 1;
  int t = ((bx >> 3) << 1) | (bx & 1);        // q-tile index 0..63
  int tid = threadIdx.x, w = tid >> 6, lane = tid & 63, b15 = lane & 15, g = lane >> 4;
  int qbase = t * 64 + w * 16;
  int qrow = qbase + b15;

  // Q fragments (B-operand: col=q, k=d) -- 8 x 16B contiguous loads
  const u16* Qp = Qs + (size_t)(batch * 4096 + qrow) * 256;
  bf16x8 qf[8];
#pragma unroll
  for (int kk = 0; kk < 8; ++kk) qf[kk] = *(const bf16x8*)(Qp + kk * 32 + g * 8);

  f32x4 acc[16] = {};
  float m = -3e38f, lsum = 0.f;
  int nkt = 2 * t + 2;

  uint4 kreg[4], vreg[4];
  auto issue_loads = [&](int kt) {
    int kv0 = kt * 32;
    const uint4* Kg = (const uint4*)(Ks_ + (size_t)(batch * 4096 + kv0) * 256);
#pragma unroll
    for (int i = 0; i < 4; ++i) kreg[i] = Kg[i * 256 + tid];
    const u16* Vg = Vt_ + (size_t)batch * 1048576 + kv0;
#pragma unroll
    for (int i = 0; i < 4; ++i) {
      int c = i * 256 + tid, e = c >> 2, cc = c & 3;
      vreg[i] = *(const uint4*)(Vg + (size_t)e * 4096 + cc * 8);
    }
  };
  auto write_lds = [&]() {
#pragma unroll
    for (int i = 0; i < 4; ++i) {
      int c = i * 256 + tid, row = c >> 5, q = c & 31;
      *(uint4*)((char*)Klds + row * 528 + q * 16) = kreg[i];
    }
#pragma unroll
    for (int i = 0; i < 4; ++i) {
      int c = i * 256 + tid, e = c >> 2, cc = c & 3;
      *(uint4*)((char*)Vlds + e * 80 + cc * 16) = vreg[i];
    }
  };

  issue_loads(0);
  write_lds();
  __syncthreads();

  for (int kt = 0; kt < nkt; ++kt) {
    if (kt + 1 < nkt) issue_loads(kt + 1);  // prefetch into regs; consumed after barrier

    // --- QK^T swapped: S^T[kv][q] = mfma(A=K, B=Q); lane owns q=b15, kv=g*4+r(+16) ---
    f32x4 s0 = {0.f, 0.f, 0.f, 0.f}, s1 = {0.f, 0.f, 0.f, 0.f};
#pragma unroll
    for (int kk = 0; kk < 8; ++kk) {
      bf16x8 k0 = *(const bf16x8*)(Klds + (size_t)b15 * 264 + kk * 32 + g * 8);
      bf16x8 k1 = *(const bf16x8*)(Klds + (size_t)(16 + b15) * 264 + kk * 32 + g * 8);
      s0 = MFMA16(k0, qf[kk], s0, 0, 0, 0);
      s1 = MFMA16(k1, qf[kk], s1, 0, 0, 0);
    }
    int kv0 = kt * 32;
    if (kv0 + 31 > qbase) {  // diagonal tile only (wave-uniform)
#pragma unroll
      for (int r = 0; r < 4; ++r) {
        if (kv0 + g * 4 + r > qrow) s0[r] = -3e38f;
        if (kv0 + 16 + g * 4 + r > qrow) s1[r] = -3e38f;
      }
    }

    // --- online softmax (base-2; scale folded into Q) ---
    float pm = fmaxf(fmaxf(fmaxf(s0[0], s0[1]), fmaxf(s0[2], s0[3])),
                     fmaxf(fmaxf(s1[0], s1[1]), fmaxf(s1[2], s1[3])));
    pm = fmaxf(pm, __shfl_xor(pm, 16));
    pm = fmaxf(pm, __shfl_xor(pm, 32));
    float mn = fmaxf(m, pm);
    float sc = exp2f(m - mn);
    float p0[4], p1[4], ps = 0.f;
#pragma unroll
    for (int r = 0; r < 4; ++r) {
      p0[r] = exp2f(s0[r] - mn);
      p1[r] = exp2f(s1[r] - mn);
      ps += p0[r] + p1[r];
    }
    ps += __shfl_xor(ps, 16);
    ps += __shfl_xor(ps, 32);
    lsum = lsum * sc + ps;
    m = mn;
#pragma unroll
    for (int eb = 0; eb < 16; ++eb) acc[eb] *= sc;

    // --- repack P (D-layout) -> PV B-operand (col=q=b15, k=kv=g*8+j) ---
    u32 f0d0 = pk2(p0[0], p0[1]), f0d1 = pk2(p0[2], p0[3]);
    u32 f1d0 = pk2(p1[0], p1[1]), f1d1 = pk2(p1[2], p1[3]);
    int srcA = b15 + 32 * (g & 1), srcB = srcA + 16;
    u32 a0 = (u32)__shfl((int)f0d0, srcA), a1 = (u32)__shfl((int)f0d1, srcA);
    u32 a2 = (u32)__shfl((int)f0d0, srcB), a3 = (u32)__shfl((int)f0d1, srcB);
    u32 c0 = (u32)__shfl((int)f1d0, srcA), c1 = (u32)__shfl((int)f1d1, srcA);
    u32 c2 = (u32)__shfl((int)f1d0, srcB), c3 = (u32)__shfl((int)f1d1, srcB);
    bool hi = (g >= 2);
    union { u32 u[4]; bf16x8 v; } pu;
    pu.u[0] = hi ? c0 : a0; pu.u[1] = hi ? c1 : a1;
    pu.u[2] = hi ? c2 : a2; pu.u[3] = hi ? c3 : a3;
    bf16x8 pb = pu.v;

    // --- PV: O^T[e][q] += mfma(A=Vt, B=P^T) ---
#pragma unroll
    for (int eb = 0; eb < 16; ++eb) {
      bf16x8 vf = *(const bf16x8*)(Vlds + (size_t)(eb * 16 + b15) * 40 + g * 8);
      acc[eb] = MFMA16(vf, pb, acc[eb], 0, 0, 0);
    }

    if (kt + 1 < nkt) {
      __syncthreads();   // everyone done reading current LDS tiles
      write_lds();       // regs -> LDS (vmcnt waited by compiler)
      __syncthreads();   // next tile visible
    }
  }

  float inv = 1.f / lsum;
  float* Op = out + (size_t)(batch * 4096 + qrow) * 256;
#pragma unroll
  for (int eb = 0; eb < 16; ++eb) {
    f32x4 o = acc[eb] * inv;
    *(f32x4*)(Op + eb * 16 + g * 4) = o;
  }
}

// ---------------- launch ----------------
extern "C" void kernel_launch(void* const* d_in, const int* in_sizes, int n_in,
                              void* d_out, int out_size, void* d_ws, size_t ws_size,
                              hipStream_t stream) {
  const float* x = (const float*)d_in[0];
  const float* wq = (const float*)d_in[1];
  const float* wk = (const float*)d_in[2];
  const float* wv = (const float*)d_in[3];
  char* ws = (char*)d_ws;
  u16* xbf = (u16*)(ws);                  // 8 MB  [16384][256] bf16
  u16* wbf = (u16*)(ws + 8388608);        // 384KB [3][256][256] bf16
  u16* Qs  = (u16*)(ws + 9437184);        // 8 MB  [4][4096][256] bf16 (pre-scaled)
  u16* Ks  = (u16*)(ws + 17825792);       // 8 MB  [4][4096][256] bf16
  u16* Vt  = (u16*)(ws + 26214400);       // 8 MB  [4][256][4096] bf16
  float* out = (float*)d_out;

  hipLaunchKernelGGL(cvt_kernel, dim3(4288), dim3(256), 0, stream, x, wq, wk, wv, xbf, wbf);
  hipLaunchKernelGGL(proj_kernel, dim3(256, 3), dim3(256), 0, stream, xbf, wbf, Qs, Ks, Vt);
  hipLaunchKernelGGL(attn_kernel, dim3(256), dim3(256), 0, stream, Qs, Ks, Vt, out);
}

// Round 2
// 215.670 us; speedup vs baseline: 2.3192x; 2.3192x over previous
//
#include <hip/hip_runtime.h>

typedef unsigned short u16;
typedef unsigned int u32;
typedef __attribute__((ext_vector_type(8))) short bf16x8;
typedef __attribute__((ext_vector_type(4))) float f32x4;

#define MFMA16 __builtin_amdgcn_mfma_f32_16x16x32_bf16

__device__ __forceinline__ u16 f2bf(float f) {
  u32 u = __builtin_bit_cast(u32, f);
  u = u + 0x7FFFu + ((u >> 16) & 1u);
  return (u16)(u >> 16);
}
__device__ __forceinline__ u32 pk2(float lo, float hi) {
  return (u32)f2bf(lo) | ((u32)f2bf(hi) << 16);
}
__device__ __forceinline__ float bf2f(u32 x) {
  return __builtin_bit_cast(float, x << 16);
}
__device__ __forceinline__ void gld16(const void* gp, void* lp) {
  __builtin_amdgcn_global_load_lds((const __attribute__((address_space(1))) u32*)gp,
                                   (__attribute__((address_space(3))) u32*)lp, 16, 0, 0);
}

// ---------------- kernel 0: fp32 -> bf16 convert (x, Wq|Wk|Wv) ----------------
__global__ __launch_bounds__(256) void cvt_kernel(
    const float* __restrict__ x, const float* __restrict__ wq,
    const float* __restrict__ wk, const float* __restrict__ wv,
    u16* __restrict__ xbf, u16* __restrict__ wbf) {
  int idx = blockIdx.x * 256 + threadIdx.x;
  if (idx < 1048576) {
    float4 v = ((const float4*)x)[idx];
    uint2 u; u.x = pk2(v.x, v.y); u.y = pk2(v.z, v.w);
    ((uint2*)xbf)[idx] = u;
  } else {
    int j = idx - 1048576;
    const float* W = (j < 16384) ? wq : (j < 32768) ? wk : wv;
    int k = j & 16383;
    float4 v = ((const float4*)W)[k];
    uint2 u; u.x = pk2(v.x, v.y); u.y = pk2(v.z, v.w);
    ((uint2*)wbf)[j] = u;
  }
}

// ---------------- kernel 1: QKV projection ----------------
// mat 0: Qs[s][e] = (x @ Wq^T) * (log2(e)/16)
// mat 1: Ks[s][e] =  x @ Wk^T
// mat 2: Vt[e][s] =  (x @ Wv^T)^T
__global__ __launch_bounds__(256, 2) void proj_kernel(
    const u16* __restrict__ xbf, const u16* __restrict__ wbf,
    u16* __restrict__ Qs, u16* __restrict__ Ks, u16* __restrict__ Vt) {
  int tile = blockIdx.x, mat = blockIdx.y;
  int tid = threadIdx.x, w = tid >> 6, lane = tid & 63, b15 = lane & 15, g = lane >> 4;
  int base = tile * 64 + w * 16;
  const u16* W = wbf + mat * 65536;
  const u16* Xp = xbf + (size_t)(base + b15) * 256;
  f32x4 acc[16] = {};
  if (mat < 2) {
#pragma unroll
    for (int kk = 0; kk < 8; ++kk) {
      bf16x8 xf = *(const bf16x8*)(Xp + kk * 32 + g * 8);
#pragma unroll
      for (int eb = 0; eb < 16; ++eb) {
        bf16x8 wf = *(const bf16x8*)(W + (size_t)(eb * 16 + b15) * 256 + kk * 32 + g * 8);
        acc[eb] = MFMA16(xf, wf, acc[eb], 0, 0, 0);
      }
    }
    float scale = (mat == 0) ? 0.0901684400555602f : 1.0f;  // log2(e)/16
    u16* dst = (mat == 0) ? Qs : Ks;
#pragma unroll
    for (int eb = 0; eb < 16; ++eb)
#pragma unroll
      for (int r = 0; r < 4; ++r)
        dst[(size_t)(base + g * 4 + r) * 256 + eb * 16 + b15] = f2bf(acc[eb][r] * scale);
  } else {
#pragma unroll
    for (int kk = 0; kk < 8; ++kk) {
      bf16x8 xf = *(const bf16x8*)(Xp + kk * 32 + g * 8);
#pragma unroll
      for (int eb = 0; eb < 16; ++eb) {
        bf16x8 wf = *(const bf16x8*)(W + (size_t)(eb * 16 + b15) * 256 + kk * 32 + g * 8);
        acc[eb] = MFMA16(wf, xf, acc[eb], 0, 0, 0);
      }
    }
    int sglob = base + b15;
    int b = sglob >> 12, sl = sglob & 4095;
#pragma unroll
    for (int eb = 0; eb < 16; ++eb)
#pragma unroll
      for (int r = 0; r < 4; ++r) {
        int e = eb * 16 + g * 4 + r;
        Vt[((size_t)(b * 256 + e) << 12) + sl] = f2bf(acc[eb][r]);
      }
  }
}

// ---------------- kernel 2: causal flash attention, kv-split partials ----------------
// Unit = (batch b, q-tile tt of 128 rows, kv-chunk c of 512). 576 blocks, 4 waves,
// 32 q-rows/wave. K/V staged via global_load_lds, double-buffered, XOR-swizzled
// (pre-swizzled global source, swizzled LDS read). One barrier per kv-step; next
// tile's loads issued right after the barrier -> in flight under compute.
__global__ __launch_bounds__(256, 2) void attn_kernel(
    const u16* __restrict__ Qs, const u16* __restrict__ Ks_,
    const u16* __restrict__ Vt_, u16* __restrict__ pacc, float2* __restrict__ pml) {
  __shared__ u16 Kd[2][8192];   // [buf][32 kv rows][256 d], 512B rows, swz byte^=(row&7)<<4
  __shared__ u16 Vd[2][8192];   // [buf][256 e rows][32 kv], 64B rows, quad-swz

  int bid = blockIdx.x;
  int xcd = bid & 7;
  int b = xcd >> 1;                       // batch -> XCD pair (L2 affinity)
  int u = (bid >> 3) * 2 + (xcd & 1);     // 0..143
  int g4 = 0;
#pragma unroll
  for (int t = 1; t <= 7; ++t) g4 += (u >= 2 * t * (t + 1)) ? 1 : 0;
  int v = u - 2 * g4 * (g4 + 1);
  int tt = 4 * g4 + v / (g4 + 1);         // q-tile 0..31
  int c = v % (g4 + 1);                   // chunk within tile
  int uid = b * 144 + u;

  int tid = threadIdx.x, w = tid >> 6, lane = tid & 63, b15 = lane & 15, g = lane >> 4;
  int qbase = tt * 128 + w * 32;
  int kt0 = c * 16, kt_end = min(kt0 + 16, 4 * (tt + 1));

  // loop-invariant staging offsets (inverse swizzle: LDS stays linear, source permuted)
  int Koff[4], Voff[4];
#pragma unroll
  for (int i = 0; i < 4; ++i) {
    int o = (w * 4 + i) * 1024 + lane * 16;
    int row = o >> 9;
    Koff[i] = row * 512 + ((o & 511) ^ ((row & 7) << 4));
    int e17 = o >> 7;
    int e = (e17 << 1) | (((o >> 6) & 1) ^ ((e17 >> 2) & 1));
    int gg = ((o >> 4) & 3) ^ (e17 & 3);
    Voff[i] = e * 8192 + gg * 16;
  }
  const char* Kgb = (const char*)(Ks_ + (size_t)b * 4096 * 256);
  const char* Vgb = (const char*)(Vt_ + (size_t)b * 1048576);
  char* KL = (char*)&Kd[0][0];
  char* VL = (char*)&Vd[0][0];

  auto stage = [&](int buf, int kt) {
    size_t kb = (size_t)kt * 32 * 512;   // K byte offset of chunk rows
    size_t vb = (size_t)kt * 64;         // V: kv0*2 bytes within each e-row
#pragma unroll
    for (int i = 0; i < 4; ++i)
      gld16(Kgb + kb + Koff[i], KL + buf * 16384 + (w * 4 + i) * 1024);
#pragma unroll
    for (int i = 0; i < 4; ++i)
      gld16(Vgb + vb + Voff[i], VL + buf * 16384 + (w * 4 + i) * 1024);
  };

  // Q fragments for both 16-row halves (B-operand: col=q, k=d)
  const u16* Qp0 = Qs + ((size_t)b * 4096 + qbase + b15) * 256;
  bf16x8 qf0[8], qf1[8];
#pragma unroll
  for (int kk = 0; kk < 8; ++kk) {
    qf0[kk] = *(const bf16x8*)(Qp0 + kk * 32 + g * 8);
    qf1[kk] = *(const bf16x8*)(Qp0 + 16 * 256 + kk * 32 + g * 8);
  }

  f32x4 acc0[16] = {}, acc1[16] = {};
  float m0 = -3e38f, l0 = 0.f, m1 = -3e38f, l1 = 0.f;
  stage(0, kt0);
  int cur = 0;

  for (int kt = kt0; kt < kt_end; ++kt) {
    __syncthreads();                         // buf[cur] landed (vmcnt drained here)
    if (kt + 1 < kt_end) stage(cur ^ 1, kt + 1);  // fly during compute
    int kv0 = kt * 32;
    if (kv0 <= qbase + 31) {                 // wave has live rows this step
      const char* Kc = KL + cur * 16384;
      const char* Vc = VL + cur * 16384;
      f32x4 s00 = {0,0,0,0}, s10 = {0,0,0,0}, s01 = {0,0,0,0}, s11 = {0,0,0,0};
#pragma unroll
      for (int kk = 0; kk < 8; ++kk) {
        int cb = (kk * 64 + g * 16) ^ ((b15 & 7) << 4);
        bf16x8 k0 = *(const bf16x8*)(Kc + b15 * 512 + cb);
        bf16x8 k1 = *(const bf16x8*)(Kc + (16 + b15) * 512 + cb);
        s00 = MFMA16(k0, qf0[kk], s00, 0, 0, 0);
        s10 = MFMA16(k1, qf0[kk], s10, 0, 0, 0);
        s01 = MFMA16(k0, qf1[kk], s01, 0, 0, 0);
        s11 = MFMA16(k1, qf1[kk], s11, 0, 0, 0);
      }
      if (kv0 + 31 > qbase) {  // diagonal: mask kv > qrow
        int q0 = qbase + b15, q1 = q0 + 16;
#pragma unroll
        for (int r = 0; r < 4; ++r) {
          int ka = kv0 + g * 4 + r, kb2 = ka + 16;
          if (ka > q0) s00[r] = -3e38f;
          if (kb2 > q0) s10[r] = -3e38f;
          if (ka > q1) s01[r] = -3e38f;
          if (kb2 > q1) s11[r] = -3e38f;
        }
      }
      bf16x8 pb0, pb1;
      {  // softmax + repack, half 0
        float pm = fmaxf(fmaxf(fmaxf(s00[0], s00[1]), fmaxf(s00[2], s00[3])),
                         fmaxf(fmaxf(s10[0], s10[1]), fmaxf(s10[2], s10[3])));
        pm = fmaxf(pm, __shfl_xor(pm, 16));
        pm = fmaxf(pm, __shfl_xor(pm, 32));
        float mn = fmaxf(m0, pm);
        float sc = exp2f(m0 - mn);
        float p0[4], p1[4], ps = 0.f;
#pragma unroll
        for (int r = 0; r < 4; ++r) {
          p0[r] = exp2f(s00[r] - mn); p1[r] = exp2f(s10[r] - mn);
          ps += p0[r] + p1[r];
        }
        ps += __shfl_xor(ps, 16);
        ps += __shfl_xor(ps, 32);
        l0 = l0 * sc + ps; m0 = mn;
#pragma unroll
        for (int eb = 0; eb < 16; ++eb) acc0[eb] *= sc;
        u32 f0d0 = pk2(p0[0], p0[1]), f0d1 = pk2(p0[2], p0[3]);
        u32 f1d0 = pk2(p1[0], p1[1]), f1d1 = pk2(p1[2], p1[3]);
        int srcA = b15 + 32 * (g & 1), srcB = srcA + 16;
        u32 a0 = (u32)__shfl((int)f0d0, srcA), a1 = (u32)__shfl((int)f0d1, srcA);
        u32 a2 = (u32)__shfl((int)f0d0, srcB), a3 = (u32)__shfl((int)f0d1, srcB);
        u32 c0 = (u32)__shfl((int)f1d0, srcA), c1 = (u32)__shfl((int)f1d1, srcA);
        u32 c2 = (u32)__shfl((int)f1d0, srcB), c3 = (u32)__shfl((int)f1d1, srcB);
        bool hi = (g >= 2);
        union { u32 uu[4]; bf16x8 vv; } pu;
        pu.uu[0] = hi ? c0 : a0; pu.uu[1] = hi ? c1 : a1;
        pu.uu[2] = hi ? c2 : a2; pu.uu[3] = hi ? c3 : a3;
        pb0 = pu.vv;
      }
      {  // softmax + repack, half 1
        float pm = fmaxf(fmaxf(fmaxf(s01[0], s01[1]), fmaxf(s01[2], s01[3])),
                         fmaxf(fmaxf(s11[0], s11[1]), fmaxf(s11[2], s11[3])));
        pm = fmaxf(pm, __shfl_xor(pm, 16));
        pm = fmaxf(pm, __shfl_xor(pm, 32));
        float mn = fmaxf(m1, pm);
        float sc = exp2f(m1 - mn);
        float p0[4], p1[4], ps = 0.f;
#pragma unroll
        for (int r = 0; r < 4; ++r) {
          p0[r] = exp2f(s01[r] - mn); p1[r] = exp2f(s11[r] - mn);
          ps += p0[r] + p1[r];
        }
        ps += __shfl_xor(ps, 16);
        ps += __shfl_xor(ps, 32);
        l1 = l1 * sc + ps; m1 = mn;
#pragma unroll
        for (int eb = 0; eb < 16; ++eb) acc1[eb] *= sc;
        u32 f0d0 = pk2(p0[0], p0[1]), f0d1 = pk2(p0[2], p0[3]);
        u32 f1d0 = pk2(p1[0], p1[1]), f1d1 = pk2(p1[2], p1[3]);
        int srcA = b15 + 32 * (g & 1), srcB = srcA + 16;
        u32 a0 = (u32)__shfl((int)f0d0, srcA), a1 = (u32)__shfl((int)f0d1, srcA);
        u32 a2 = (u32)__shfl((int)f0d0, srcB), a3 = (u32)__shfl((int)f0d1, srcB);
        u32 c0 = (u32)__shfl((int)f1d0, srcA), c1 = (u32)__shfl((int)f1d1, srcA);
        u32 c2 = (u32)__shfl((int)f1d0, srcB), c3 = (u32)__shfl((int)f1d1, srcB);
        bool hi = (g >= 2);
        union { u32 uu[4]; bf16x8 vv; } pu;
        pu.uu[0] = hi ? c0 : a0; pu.uu[1] = hi ? c1 : a1;
        pu.uu[2] = hi ? c2 : a2; pu.uu[3] = hi ? c3 : a3;
        pb1 = pu.vv;
      }
      // PV: V fragment read once, used for both q-halves
#pragma unroll
      for (int eb = 0; eb < 16; ++eb) {
        int e = eb * 16 + b15;
        bf16x8 vf = *(const bf16x8*)(Vc + ((e << 6) ^ (((((e >> 1) & 7)) ^ g) << 4)));
        acc0[eb] = MFMA16(vf, pb0, acc0[eb], 0, 0, 0);
        acc1[eb] = MFMA16(vf, pb1, acc1[eb], 0, 0, 0);
      }
    }
    cur ^= 1;
  }

  // store partials (unnormalized acc in bf16, m/l in fp32)
  u16* pp0 = pacc + ((size_t)uid * 128 + w * 32 + b15) * 256;
  u16* pp1 = pp0 + 16 * 256;
#pragma unroll
  for (int eb = 0; eb < 16; ++eb) {
    uint2 u0, u1;
    u0.x = pk2(acc0[eb][0], acc0[eb][1]); u0.y = pk2(acc0[eb][2], acc0[eb][3]);
    u1.x = pk2(acc1[eb][0], acc1[eb][1]); u1.y = pk2(acc1[eb][2], acc1[eb][3]);
    *(uint2*)(pp0 + eb * 16 + g * 4) = u0;
    *(uint2*)(pp1 + eb * 16 + g * 4) = u1;
  }
  if (g == 0) {
    float2 a; a.x = m0; a.y = l0;
    float2 bb; bb.x = m1; bb.y = l1;
    pml[(size_t)uid * 128 + w * 32 + b15] = a;
    pml[(size_t)uid * 128 + w * 32 + 16 + b15] = bb;
  }
}

// ---------------- kernel 3: combine partials ----------------
__global__ __launch_bounds__(256) void combine_kernel(
    const u16* __restrict__ pacc, const float2* __restrict__ pml,
    float* __restrict__ out) {
  int row = blockIdx.x * 4 + (threadIdx.x >> 6);
  int lane = threadIdx.x & 63;
  int b = row >> 12, r = row & 4095;
  int tt = r >> 7, rin = r & 127;
  int g4 = tt >> 2, nch = g4 + 1;
  int ubase = b * 144 + 2 * g4 * (g4 + 1) + (tt & 3) * (g4 + 1);
  float M = -3e38f;
  for (int cc = 0; cc < nch; ++cc)
    M = fmaxf(M, pml[(size_t)(ubase + cc) * 128 + rin].x);
  float L = 0.f, o0 = 0.f, o1 = 0.f, o2 = 0.f, o3 = 0.f;
  for (int cc = 0; cc < nch; ++cc) {
    float2 ml = pml[(size_t)(ubase + cc) * 128 + rin];
    float s = exp2f(ml.x - M);
    L += ml.y * s;
    uint2 a = *(const uint2*)(pacc + ((size_t)(ubase + cc) * 128 + rin) * 256 + lane * 4);
    o0 += s * bf2f(a.x & 0xffffu); o1 += s * bf2f(a.x >> 16);
    o2 += s * bf2f(a.y & 0xffffu); o3 += s * bf2f(a.y >> 16);
  }
  float inv = 1.f / L;
  f32x4 res = {o0 * inv, o1 * inv, o2 * inv, o3 * inv};
  *(f32x4*)(out + (size_t)row * 256 + lane * 4) = res;
}

// ---------------- launch ----------------
extern "C" void kernel_launch(void* const* d_in, const int* in_sizes, int n_in,
                              void* d_out, int out_size, void* d_ws, size_t ws_size,
                              hipStream_t stream) {
  const float* x = (const float*)d_in[0];
  const float* wq = (const float*)d_in[1];
  const float* wk = (const float*)d_in[2];
  const float* wv = (const float*)d_in[3];
  char* ws = (char*)d_ws;
  u16* xbf = (u16*)(ws);                    // 8 MB
  u16* wbf = (u16*)(ws + 8388608);          // 384 KB
  u16* Qs  = (u16*)(ws + 9437184);          // 8 MB (pre-scaled)
  u16* Ks  = (u16*)(ws + 17825792);         // 8 MB
  u16* Vt  = (u16*)(ws + 26214400);         // 8 MB [b][e][s]
  u16* pacc = (u16*)(ws + 34603008);        // 36 MB partial acc (bf16)
  float2* pml = (float2*)(ws + 72351744);   // 576 KB partial m/l
  float* out = (float*)d_out;

  hipLaunchKernelGGL(cvt_kernel, dim3(4288), dim3(256), 0, stream, x, wq, wk, wv, xbf, wbf);
  hipLaunchKernelGGL(proj_kernel, dim3(256, 3), dim3(256), 0, stream, xbf, wbf, Qs, Ks, Vt);
  hipLaunchKernelGGL(attn_kernel, dim3(576), dim3(256), 0, stream, Qs, Ks, Vt, pacc, pml);
  hipLaunchKernelGGL(combine_kernel, dim3(4096), dim3(256), 0, stream, pacc, pml, out);
}